// Round 14
// baseline (143.748 us; speedup 1.0000x reference)
//
#include <hip/hip_runtime.h>

typedef float f32x4 __attribute__((ext_vector_type(4)));
typedef float f32x16 __attribute__((ext_vector_type(16)));
typedef __bf16 bf16x8 __attribute__((ext_vector_type(8)));
typedef unsigned short u16x8 __attribute__((ext_vector_type(8)));
typedef int i32x2 __attribute__((ext_vector_type(2)));
typedef int i32x4 __attribute__((ext_vector_type(4)));

#define DEV static __device__ __forceinline__

DEV float bf2f(unsigned short h) {
  unsigned int u = ((unsigned int)h) << 16;
  return __builtin_bit_cast(float, u);
}
DEV unsigned short f2bf(float f) {
  unsigned int u = __builtin_bit_cast(unsigned int, f);
  u += 0x7fff + ((u >> 16) & 1);   // RTNE
  return (unsigned short)(u >> 16);
}

DEV void g2l16(const void* g, void* l) {
  __builtin_amdgcn_global_load_lds(
      (const __attribute__((address_space(1))) void*)g,
      (__attribute__((address_space(3))) void*)l, 16, 0, 0);
}

DEV unsigned int cvtpk(float lo, float hi) {
  unsigned int r;
  asm("v_cvt_pk_bf16_f32 %0, %1, %2" : "=v"(r) : "v"(lo), "v"(hi));
  return r;
}

// raw hardware exp2: |S| bounded (<18); v_exp_f32(-inf)=0 handles the mask.
DEV float fexp2(float x) {
  float r;
  asm("v_exp_f32 %0, %1" : "=v"(r) : "v"(x));
  return r;
}

// ---------------- fused converts + RoPE table ----------------
DEV void cvt8(const float* __restrict__ in, unsigned short* __restrict__ out, int idx) {
  int i = idx * 8;
  float4 a = *(const float4*)(in + i);
  float4 b = *(const float4*)(in + i + 4);
  u16x8 r;
  r[0] = f2bf(a.x); r[1] = f2bf(a.y); r[2] = f2bf(a.z); r[3] = f2bf(a.w);
  r[4] = f2bf(b.x); r[5] = f2bf(b.y); r[6] = f2bf(b.z); r[7] = f2bf(b.w);
  *(u16x8*)(out + i) = r;
}

__global__ __launch_bounds__(256) void k_cvt_all(const float* __restrict__ x,
                                                 const float* __restrict__ wq,
                                                 const float* __restrict__ wk,
                                                 const float* __restrict__ wv,
                                                 const float* __restrict__ wo,
                                                 unsigned short* __restrict__ xb,
                                                 unsigned short* __restrict__ wcat,
                                                 unsigned short* __restrict__ wob,
                                                 float2* __restrict__ rope) {
  const int blk = blockIdx.x, tid = threadIdx.x;
  if (blk < 4096) {
    cvt8(x, xb, blk * 256 + tid);
  } else if (blk < 4608) {
    cvt8(wq, wcat, (blk - 4096) * 256 + tid);
  } else if (blk < 4736) {
    cvt8(wk, wcat + 1048576, (blk - 4608) * 256 + tid);
  } else if (blk < 4864) {
    cvt8(wv, wcat + 1310720, (blk - 4736) * 256 + tid);
  } else if (blk < 5376) {
    cvt8(wo, wob, (blk - 4864) * 256 + tid);
  } else {
    int idx = (blk - 5376) * 256 + tid;   // [0, 65536)
    int s = idx >> 5, dmod = idx & 31;
    float inv_freq = powf(10000.0f, -(float)dmod * (1.0f / 32.0f));
    float sn, cs;
    sincosf((float)s * inv_freq, &sn, &cs);
    rope[idx] = make_float2(cs, sn);
  }
}

// ---------------- fused QKV GEMM + RMSNorm/RoPE/gain + fragment-layout K/V ----------------
// q: row-major via coalesced LDS path. k: fragment-major DIRECTLY from the LDS
// tile (k_krepack eliminated). v: LDS transpose -> fragment-major vt2.
__global__ __launch_bounds__(256) void k_qkv(const unsigned short* __restrict__ A,
                                             const unsigned short* __restrict__ B,
                                             const float* __restrict__ qg,
                                             const float2* __restrict__ rope,
                                             unsigned short* __restrict__ qn,
                                             unsigned short* __restrict__ kn2,
                                             unsigned short* __restrict__ vt2) {
  __shared__ unsigned short LDS[16384];
  unsigned short* As = LDS;
  unsigned short* Bs = LDS + 8192;
  const int K = 1024;
  const int tid = threadIdx.x;
  const int wid = tid >> 6, lane = tid & 63;
  const int g = lane >> 4, r16 = lane & 15;
  const int m0 = blockIdx.x * 128;
  const int y = blockIdx.y;
  const int n0 = y * 128;
  const int wr = wid >> 1, wc = wid & 1;

  f32x4 acc[4][4];
#pragma unroll
  for (int i = 0; i < 4; ++i)
#pragma unroll
    for (int j = 0; j < 4; ++j) acc[i][j] = f32x4{0.f, 0.f, 0.f, 0.f};

  const int cb = (lane & 7) * 16;

  for (int k0 = 0; k0 < K; k0 += 64) {
#pragma unroll
    for (int c = 0; c < 4; ++c) {
      int i = wid * 4 + c;
      int row = i * 8 + (lane >> 3);
      int sc = cb ^ ((row & 7) << 4);
      g2l16((const char*)A + ((size_t)(m0 + row) * K + k0) * 2 + sc, (char*)As + i * 1024);
      g2l16((const char*)B + ((size_t)(n0 + row) * K + k0) * 2 + sc, (char*)Bs + i * 1024);
    }
    __syncthreads();
#pragma unroll
    for (int kh = 0; kh < 2; ++kh) {
      bf16x8 af[4], bfr[4];
#pragma unroll
      for (int m = 0; m < 4; ++m) {
        int row = wr * 64 + m * 16 + r16;
        int byte = row * 128 + ((g * 16 + kh * 64) ^ ((row & 7) << 4));
        af[m] = *(const bf16x8*)((const char*)As + byte);
      }
#pragma unroll
      for (int n = 0; n < 4; ++n) {
        int row = wc * 64 + n * 16 + r16;
        int byte = row * 128 + ((g * 16 + kh * 64) ^ ((row & 7) << 4));
        bfr[n] = *(const bf16x8*)((const char*)Bs + byte);
      }
#pragma unroll
      for (int m = 0; m < 4; ++m)
#pragma unroll
        for (int n = 0; n < 4; ++n)
          acc[m][n] = __builtin_amdgcn_mfma_f32_16x16x32_bf16(af[m], bfr[n], acc[m][n], 0, 0, 0);
    }
    __syncthreads();
  }

  if (y < 10) {
    // ---- q/k epilogue: RMSNorm + RoPE (+gain) -> LDS [tok128][d128] tile ----
    const bool isq = (y < 8);
    const int head = isq ? (2 * y + wc) : (2 * (y - 8) + wc);
    const float gain = isq ? qg[head] * 0.18033688011112042f : 1.0f;  // fold 1/8*log2e into q
    unsigned short* T = LDS;  // byte = tok*256 + ((d*2) ^ ((tok&15)<<4))
#pragma unroll
    for (int m = 0; m < 4; ++m)
#pragma unroll
      for (int j = 0; j < 4; ++j) {
        int tokl = wr * 64 + m * 16 + g * 4 + j;
        int tok = m0 + tokl;
        int s = tok & 2047;
        float v0 = acc[m][0][j], v1 = acc[m][1][j], v2 = acc[m][2][j], v3 = acc[m][3][j];
        float ss = v0 * v0 + v1 * v1 + v2 * v2 + v3 * v3;
        ss += __shfl_xor(ss, 1); ss += __shfl_xor(ss, 2);
        ss += __shfl_xor(ss, 4); ss += __shfl_xor(ss, 8);
        float rs = rsqrtf(ss * (1.0f / 64.0f) + 1e-6f) * gain;
        float2 cs0 = rope[s * 32 + r16];
        float2 cs1 = rope[s * 32 + 16 + r16];
        float o0 = (v0 * cs0.x + v2 * cs0.y) * rs;
        float o2 = (v2 * cs0.x - v0 * cs0.y) * rs;
        float o1 = (v1 * cs1.x + v3 * cs1.y) * rs;
        float o3 = (v3 * cs1.x - v1 * cs1.y) * rs;
        char* rowb = (char*)T + tokl * 256;
        const int sw = (tokl & 15) << 4;
        const int dbase = wc * 128 + r16 * 2;   // byte of d = wc*64 + r16
        *(unsigned short*)(rowb + ((dbase) ^ sw)) = f2bf(o0);
        *(unsigned short*)(rowb + ((dbase + 32) ^ sw)) = f2bf(o1);
        *(unsigned short*)(rowb + ((dbase + 64) ^ sw)) = f2bf(o2);
        *(unsigned short*)(rowb + ((dbase + 96) ^ sw)) = f2bf(o3);
      }
    __syncthreads();
    if (isq) {
      const int row0 = tid >> 4, cl = tid & 15;
      unsigned short* dstb = qn + 2 * y * 64;
#pragma unroll
      for (int it = 0; it < 8; ++it) {
        int row = it * 16 + row0;
        i32x4 w = *(const i32x4*)((const char*)T + row * 256 + ((cl * 16) ^ ((row & 15) << 4)));
        *(i32x4*)(dstb + (size_t)(m0 + row) * 1024 + cl * 8) = w;
      }
    } else {
      // ---- k: fragment-major stores straight from T ----
      const int b_ = m0 >> 11;
      const int kb0 = (m0 & 2047) >> 5;      // first 32-key block of this tile
      const int fu = tid >> 3, sub = tid & 7;
      const int hsel = fu >> 4, kb = (fu >> 2) & 3, m = fu & 3;
      const int headk = 2 * (y - 8) + hsel;
      unsigned short* dst =
          kn2 + ((size_t)((b_ * 4 + headk) * 64 + kb0 + kb) * 4 + m) * 512;
#pragma unroll
      for (int k = 0; k < 8; ++k) {
        int slot = k * 8 + sub;
        int kw = slot & 31, hi8 = slot >> 5;
        int tokl = kb * 32 + kw;
        int d0 = hsel * 64 + m * 16 + hi8 * 8;
        i32x4 w = *(const i32x4*)((const char*)T + tokl * 256 + ((d0 * 2) ^ ((tokl & 15) << 4)));
        *(i32x4*)(dst + slot * 8) = w;
      }
    }
  } else {
    // ---- v epilogue: LDS transpose -> fragment-major vt2 ----
    unsigned short* T = LDS;
#pragma unroll
    for (int m = 0; m < 4; ++m)
#pragma unroll
      for (int n = 0; n < 4; ++n)
#pragma unroll
        for (int j = 0; j < 4; ++j) {
          int tokl = wr * 64 + m * 16 + g * 4 + j;
          int dl = wc * 64 + n * 16 + r16;
          int byte = (dl * 256 + tokl * 2) ^ ((dl & 15) << 4);
          *(unsigned short*)((char*)T + byte) = f2bf(acc[m][n][j]);
        }
    __syncthreads();
    const int d = tid >> 1, th = tid & 1;
    const int hv = 2 * (y - 10) + (d >> 6), dh = d & 63;
    const int bb = m0 >> 11;
    const int s0 = (m0 & 2047) + th * 64;
    const int kb64 = s0 >> 6;
    const int db = dh >> 5, d31 = dh & 31;
    const size_t vb0 = ((size_t)(bb * 4 + hv) * 32 + kb64) * 8 + db * 4;
    const int swz = (d & 15) << 4;
#pragma unroll
    for (int c = 0; c < 8; ++c) {
      i32x4 w = *(const i32x4*)((const char*)T + ((d * 256 + th * 128 + c * 16) ^ swz));
      *(i32x4*)(vt2 + (vb0 + (c >> 1)) * 512 + ((c & 1) * 32 + d31) * 8) = w;
    }
  }
}

// ---------------- NT GEMM (m97) for out-proj ----------------
__global__ __launch_bounds__(256) void k_gemm_bt(const unsigned short* __restrict__ A,
                                                 const unsigned short* __restrict__ B,
                                                 float* __restrict__ C, int M, int N, int K) {
  __shared__ unsigned short As[128 * 64];
  __shared__ unsigned short Bs[128 * 64];
  const int tid = threadIdx.x;
  const int wid = tid >> 6, lane = tid & 63;
  const int g = lane >> 4, r16 = lane & 15;
  const int m0 = blockIdx.x * 128, n0 = blockIdx.y * 128;
  const int wr = wid >> 1, wc = wid & 1;

  f32x4 acc[4][4];
#pragma unroll
  for (int i = 0; i < 4; ++i)
#pragma unroll
    for (int j = 0; j < 4; ++j) acc[i][j] = f32x4{0.f, 0.f, 0.f, 0.f};

  const int cb = (lane & 7) * 16;

  for (int k0 = 0; k0 < K; k0 += 64) {
#pragma unroll
    for (int c = 0; c < 4; ++c) {
      int i = wid * 4 + c;
      int row = i * 8 + (lane >> 3);
      int sc = cb ^ ((row & 7) << 4);
      g2l16((const char*)A + ((size_t)(m0 + row) * K + k0) * 2 + sc, (char*)As + i * 1024);
      g2l16((const char*)B + ((size_t)(n0 + row) * K + k0) * 2 + sc, (char*)Bs + i * 1024);
    }
    __syncthreads();
#pragma unroll
    for (int kh = 0; kh < 2; ++kh) {
      bf16x8 af[4], bfr[4];
#pragma unroll
      for (int m = 0; m < 4; ++m) {
        int row = wr * 64 + m * 16 + r16;
        int byte = row * 128 + ((g * 16 + kh * 64) ^ ((row & 7) << 4));
        af[m] = *(const bf16x8*)((const char*)As + byte);
      }
#pragma unroll
      for (int n = 0; n < 4; ++n) {
        int row = wc * 64 + n * 16 + r16;
        int byte = row * 128 + ((g * 16 + kh * 64) ^ ((row & 7) << 4));
        bfr[n] = *(const bf16x8*)((const char*)Bs + byte);
      }
#pragma unroll
      for (int m = 0; m < 4; ++m)
#pragma unroll
        for (int n = 0; n < 4; ++n)
          acc[m][n] = __builtin_amdgcn_mfma_f32_16x16x32_bf16(af[m], bfr[n], acc[m][n], 0, 0, 0);
    }
    __syncthreads();
  }
#pragma unroll
  for (int m = 0; m < 4; ++m)
#pragma unroll
    for (int n = 0; n < 4; ++n)
#pragma unroll
      for (int j = 0; j < 4; ++j) {
        int row = m0 + wr * 64 + m * 16 + g * 4 + j;
        int col = n0 + wc * 64 + n * 16 + r16;
        C[(size_t)row * N + col] = acc[m][n][j];
      }
}

// ---------------- causal GQA flash attention: 64 q-rows/wave, shared K/V reads ----
// 4 waves x 64 q-rows = 256 rows/block, grid 512 (longest-first), 64KB LDS pair dbuf.
// Each LDS fragment read feeds TWO MFMAs (q-blocks qb0/qb1) -> LDS traffic/FLOP halved,
// and qb1's QK overlaps qb0's exp/cvt/PV (in-wave ILP). l-sum in-lane (VALU) + 1 shfl.
__global__ __launch_bounds__(256) void k_attn2(const unsigned short* __restrict__ qn,
                                               const unsigned short* __restrict__ kn2,
                                               const unsigned short* __restrict__ vt2,
                                               unsigned short* __restrict__ yb) {
  __shared__ unsigned short SMEM[4 * 8192];  // 4 tile-bufs x 16 frags x 1KB
  const int tid = threadIdx.x;
  const int wid = tid >> 6, lane = tid & 63;
  const int hi = lane >> 5, l31 = lane & 31;
  const int flat = blockIdx.x;
  const int qcx = 7 - (flat >> 6);  // longest blocks dispatch first
  const int bh = flat & 63;
  const int b = bh >> 4, h = bh & 15, hv = h >> 2;
  const int q0w = qcx * 256 + wid * 64;
  const int qglob0 = q0w + l31, qglob1 = q0w + 32 + l31;
  const int tdiag0 = (q0w + 31) >> 6, tdiag1 = (q0w + 63) >> 6;
  const size_t tok0 = (size_t)b * 2048;

  bf16x8 qf0[4], qf1[4];
#pragma unroll
  for (int m = 0; m < 4; ++m) {
    qf0[m] = *(const bf16x8*)(qn + (tok0 + qglob0) * 1024 + h * 64 + m * 16 + hi * 8);
    qf1[m] = *(const bf16x8*)(qn + (tok0 + qglob1) * 1024 + h * 64 + m * 16 + hi * 8);
  }

  f32x16 oacc[2][2], zer;
#pragma unroll
  for (int r = 0; r < 16; ++r) {
    oacc[0][0][r] = 0.f; oacc[0][1][r] = 0.f;
    oacc[1][0][r] = 0.f; oacc[1][1][r] = 0.f;
    zer[r] = 0.f;
  }
  float lsum[2] = {0.f, 0.f};

  // ---- per-wave staging: wave stages 4 frags (4KB) per tile ----
  const unsigned short* srcb =
      ((wid < 2) ? kn2 : vt2) + (size_t)(b * 4 + hv) * 131072 + ((wid & 1) * 4) * 512 + lane * 8;

  auto stage = [&](int T, int tb) {
    char* dst = (char*)SMEM + tb * 16384 + wid * 4096;
    const unsigned short* s = srcb + (size_t)T * 4096;
#pragma unroll
    for (int f = 0; f < 4; ++f) g2l16(s + f * 512, dst + f * 1024);
  };

  const char* lbase = (const char*)SMEM + lane * 16;

  auto softmax_cvt = [&](f32x16* s, i32x4* paw, int qb) {
#pragma unroll
    for (int kt = 0; kt < 2; ++kt)
#pragma unroll
      for (int r = 0; r < 16; ++r) s[kt][r] = fexp2(s[kt][r]);
    float t0 = 0.f;
#pragma unroll
    for (int kt = 0; kt < 2; ++kt)
#pragma unroll
      for (int r = 0; r < 16; ++r) t0 += s[kt][r];
    lsum[qb] += t0;
#pragma unroll
    for (int kt = 0; kt < 2; ++kt)
#pragma unroll
      for (int half = 0; half < 2; ++half) {
        int bs = half * 8;
        unsigned int a0 = cvtpk(s[kt][bs + 0], s[kt][bs + 1]);
        unsigned int a1 = cvtpk(s[kt][bs + 2], s[kt][bs + 3]);
        unsigned int b0 = cvtpk(s[kt][bs + 4], s[kt][bs + 5]);
        unsigned int b1 = cvtpk(s[kt][bs + 6], s[kt][bs + 7]);
        i32x2 r0 = __builtin_amdgcn_permlane32_swap((int)a0, (int)b0, false, false);
        i32x2 r1 = __builtin_amdgcn_permlane32_swap((int)a1, (int)b1, false, false);
        i32x4 w;
        w[0] = r0[0]; w[1] = r1[0]; w[2] = r0[1]; w[3] = r1[1];
        paw[kt * 2 + half] = w;
      }
  };

  auto tile = [&](int t, int tb, bool domask) {
    if (t > tdiag1) return;
    const bool vis0 = (t <= tdiag0);
    const char* kbase = lbase + tb * 16384;
    // ---- QK: shared K-frag reads feed both q-blocks ----
    f32x16 s0[2], s1[2];
    __builtin_amdgcn_s_setprio(1);
#pragma unroll
    for (int kt = 0; kt < 2; ++kt) {
      bf16x8 kf = *(const bf16x8*)(kbase + (kt * 4) * 1024);
      s1[kt] = __builtin_amdgcn_mfma_f32_32x32x16_bf16(kf, qf1[0], zer, 0, 0, 0);
      if (vis0) s0[kt] = __builtin_amdgcn_mfma_f32_32x32x16_bf16(kf, qf0[0], zer, 0, 0, 0);
#pragma unroll
      for (int m = 1; m < 4; ++m) {
        kf = *(const bf16x8*)(kbase + (kt * 4 + m) * 1024);
        s1[kt] = __builtin_amdgcn_mfma_f32_32x32x16_bf16(kf, qf1[m], s1[kt], 0, 0, 0);
        if (vis0) s0[kt] = __builtin_amdgcn_mfma_f32_32x32x16_bf16(kf, qf0[m], s0[kt], 0, 0, 0);
      }
    }
    __builtin_amdgcn_s_setprio(0);
    // ---- causal mask (last two pairs only) ----
    if (domask) {
      const int k0 = t * 64;
#pragma unroll
      for (int kt = 0; kt < 2; ++kt)
#pragma unroll
        for (int r = 0; r < 16; ++r) {
          int key = k0 + kt * 32 + (r & 3) + 8 * (r >> 2) + 4 * hi;
          if (key > qglob1) s1[kt][r] = -INFINITY;
          if (vis0 && key > qglob0) s0[kt][r] = -INFINITY;
        }
    }
    // ---- softmax + cvt per q-block ----
    i32x4 paw0[4], paw1[4];
    if (vis0) softmax_cvt(s0, paw0, 0);
    softmax_cvt(s1, paw1, 1);
    // ---- PV: shared V-frag reads feed both q-blocks ----
    const char* vbase = lbase + tb * 16384 + 8192;
    __builtin_amdgcn_s_setprio(1);
#pragma unroll
    for (int db = 0; db < 2; ++db)
#pragma unroll
      for (int ks = 0; ks < 4; ++ks) {
        bf16x8 vf = *(const bf16x8*)(vbase + (db * 4 + ks) * 1024);
        oacc[1][db] = __builtin_amdgcn_mfma_f32_32x32x16_bf16(
            vf, __builtin_bit_cast(bf16x8, paw1[ks]), oacc[1][db], 0, 0, 0);
        if (vis0)
          oacc[0][db] = __builtin_amdgcn_mfma_f32_32x32x16_bf16(
              vf, __builtin_bit_cast(bf16x8, paw0[ks]), oacc[0][db], 0, 0, 0);
      }
    __builtin_amdgcn_s_setprio(0);
  };

  const int npair = 2 * qcx + 2;  // nt = 4*qcx + 4 tiles

  stage(0, 0);
  stage(1, 1);
  __syncthreads();

  for (int p = 0; p < npair; ++p) {
    const int pb = (p & 1) << 1;
    if (p + 1 < npair) {
      stage(2 * p + 2, pb ^ 2);
      stage(2 * p + 3, (pb ^ 2) | 1);
    }
    const bool domask = (p >= npair - 2);
    tile(2 * p, pb, domask);
    tile(2 * p + 1, pb | 1, domask);
    __syncthreads();           // drains prefetch + frees bufs pb,pb|1
  }

  // ---- epilogue per q-block: O^T -> per-wave LDS transpose -> coalesced store ----
  lsum[0] += __shfl_xor(lsum[0], 32);
  lsum[1] += __shfl_xor(lsum[1], 32);
  const int swl = (l31 & 7) << 4;
  char* obase = (char*)SMEM + wid * 4096;
#pragma unroll
  for (int qb = 0; qb < 2; ++qb) {
    const float inv = 1.0f / lsum[qb];
#pragma unroll
    for (int db = 0; db < 2; ++db)
#pragma unroll
      for (int i = 0; i < 8; ++i) {
        int r = 2 * i;
        int dim = db * 32 + (r & 3) + 8 * (r >> 2) + 4 * hi;
        unsigned int w = (unsigned int)f2bf(oacc[qb][db][r] * inv) |
                         ((unsigned int)f2bf(oacc[qb][db][r + 1] * inv) << 16);
        *(unsigned int*)(obase + l31 * 128 + ((dim * 2) ^ swl)) = w;
      }
    __syncthreads();
#pragma unroll
    for (int it = 0; it < 4; ++it) {
      int cc = it * 2 + hi;
      i32x4 w = *(const i32x4*)(obase + l31 * 128 + ((cc * 16) ^ swl));
      *(i32x4*)(yb + (tok0 + q0w + qb * 32 + l31) * 1024 + h * 64 + cc * 8) = w;
    }
    __syncthreads();
  }
}

// ---------------- launch ----------------
extern "C" void kernel_launch(void* const* d_in, const int* in_sizes, int n_in,
                              void* d_out, int out_size, void* d_ws, size_t ws_size,
                              hipStream_t stream) {
  (void)in_sizes; (void)n_in; (void)out_size; (void)ws_size;
  const float* x  = (const float*)d_in[0];
  const float* Wq = (const float*)d_in[1];
  const float* Wk = (const float*)d_in[2];
  const float* Wv = (const float*)d_in[3];
  const float* Wo = (const float*)d_in[4];
  const float* qg = (const float*)d_in[5];

  char* ws = (char*)d_ws;
  unsigned short* xb   = (unsigned short*)(ws);             // 16 MB  [8192][1024]
  unsigned short* wcat = (unsigned short*)(ws + 16777216);  // 3 MB   [1536][1024]
  unsigned short* wob  = (unsigned short*)(ws + 19922944);  // 2 MB   [1024][1024]
  unsigned short* qn   = (unsigned short*)(ws + 22020096);  // 16 MB  [8192][1024]
  unsigned short* kn2  = (unsigned short*)(ws + 38797312);  // 4 MB   fragment-major K
  unsigned short* yb   = xb;                                // alias: xb dead after k_qkv
  unsigned short* vt2  = (unsigned short*)((char*)d_out + 25165824);  // 4 MB fragment-major V
  float2*         rope = (float2*)((char*)d_out + 29360128);          // 512 KB [2048][32]

  k_cvt_all<<<5632, 256, 0, stream>>>(x, Wq, Wk, Wv, Wo, xb, wcat, wob, rope);
  k_qkv<<<dim3(64, 12), 256, 0, stream>>>(xb, wcat, qg, rope, qn, kn2, vt2);
  k_attn2<<<512, 256, 0, stream>>>(qn, kn2, vt2, yb);
  k_gemm_bt<<<dim3(64, 8), 256, 0, stream>>>(yb, wob, (float*)d_out, 8192, 1024, 1024);
}

// Round 15
// 132.688 us; speedup vs baseline: 1.0834x; 1.0834x over previous
//
#include <hip/hip_runtime.h>

typedef float f32x4 __attribute__((ext_vector_type(4)));
typedef float f32x16 __attribute__((ext_vector_type(16)));
typedef __bf16 bf16x8 __attribute__((ext_vector_type(8)));
typedef unsigned short u16x8 __attribute__((ext_vector_type(8)));
typedef int i32x2 __attribute__((ext_vector_type(2)));
typedef int i32x4 __attribute__((ext_vector_type(4)));

#define DEV static __device__ __forceinline__

DEV float bf2f(unsigned short h) {
  unsigned int u = ((unsigned int)h) << 16;
  return __builtin_bit_cast(float, u);
}
DEV unsigned short f2bf(float f) {
  unsigned int u = __builtin_bit_cast(unsigned int, f);
  u += 0x7fff + ((u >> 16) & 1);   // RTNE
  return (unsigned short)(u >> 16);
}

DEV void g2l16(const void* g, void* l) {
  __builtin_amdgcn_global_load_lds(
      (const __attribute__((address_space(1))) void*)g,
      (__attribute__((address_space(3))) void*)l, 16, 0, 0);
}

DEV unsigned int cvtpk(float lo, float hi) {
  unsigned int r;
  asm("v_cvt_pk_bf16_f32 %0, %1, %2" : "=v"(r) : "v"(lo), "v"(hi));
  return r;
}

// raw hardware exp2: |S| bounded (<18); v_exp_f32(-inf)=0 handles the mask.
DEV float fexp2(float x) {
  float r;
  asm("v_exp_f32 %0, %1" : "=v"(r) : "v"(x));
  return r;
}

// ---------------- fused converts + RoPE table ----------------
DEV void cvt8(const float* __restrict__ in, unsigned short* __restrict__ out, int idx) {
  int i = idx * 8;
  float4 a = *(const float4*)(in + i);
  float4 b = *(const float4*)(in + i + 4);
  u16x8 r;
  r[0] = f2bf(a.x); r[1] = f2bf(a.y); r[2] = f2bf(a.z); r[3] = f2bf(a.w);
  r[4] = f2bf(b.x); r[5] = f2bf(b.y); r[6] = f2bf(b.z); r[7] = f2bf(b.w);
  *(u16x8*)(out + i) = r;
}

__global__ __launch_bounds__(256) void k_cvt_all(const float* __restrict__ x,
                                                 const float* __restrict__ wq,
                                                 const float* __restrict__ wk,
                                                 const float* __restrict__ wv,
                                                 const float* __restrict__ wo,
                                                 unsigned short* __restrict__ xb,
                                                 unsigned short* __restrict__ wcat,
                                                 unsigned short* __restrict__ wob,
                                                 float2* __restrict__ rope) {
  const int blk = blockIdx.x, tid = threadIdx.x;
  if (blk < 4096) {
    cvt8(x, xb, blk * 256 + tid);
  } else if (blk < 4608) {
    cvt8(wq, wcat, (blk - 4096) * 256 + tid);
  } else if (blk < 4736) {
    cvt8(wk, wcat + 1048576, (blk - 4608) * 256 + tid);
  } else if (blk < 4864) {
    cvt8(wv, wcat + 1310720, (blk - 4736) * 256 + tid);
  } else if (blk < 5376) {
    cvt8(wo, wob, (blk - 4864) * 256 + tid);
  } else {
    int idx = (blk - 5376) * 256 + tid;   // [0, 65536)
    int s = idx >> 5, dmod = idx & 31;
    float inv_freq = powf(10000.0f, -(float)dmod * (1.0f / 32.0f));
    float sn, cs;
    sincosf((float)s * inv_freq, &sn, &cs);
    rope[idx] = make_float2(cs, sn);
  }
}

// ---------------- fused QKV GEMM + RMSNorm/RoPE/gain + fragment-layout K/V ----------------
// q: row-major via coalesced LDS path. k: fragment-major DIRECTLY from the LDS
// tile (no repack kernel). v: LDS transpose -> fragment-major vt2.
__global__ __launch_bounds__(256) void k_qkv(const unsigned short* __restrict__ A,
                                             const unsigned short* __restrict__ B,
                                             const float* __restrict__ qg,
                                             const float2* __restrict__ rope,
                                             unsigned short* __restrict__ qn,
                                             unsigned short* __restrict__ kn2,
                                             unsigned short* __restrict__ vt2) {
  __shared__ unsigned short LDS[16384];
  unsigned short* As = LDS;
  unsigned short* Bs = LDS + 8192;
  const int K = 1024;
  const int tid = threadIdx.x;
  const int wid = tid >> 6, lane = tid & 63;
  const int g = lane >> 4, r16 = lane & 15;
  const int m0 = blockIdx.x * 128;
  const int y = blockIdx.y;
  const int n0 = y * 128;
  const int wr = wid >> 1, wc = wid & 1;

  f32x4 acc[4][4];
#pragma unroll
  for (int i = 0; i < 4; ++i)
#pragma unroll
    for (int j = 0; j < 4; ++j) acc[i][j] = f32x4{0.f, 0.f, 0.f, 0.f};

  const int cb = (lane & 7) * 16;

  for (int k0 = 0; k0 < K; k0 += 64) {
#pragma unroll
    for (int c = 0; c < 4; ++c) {
      int i = wid * 4 + c;
      int row = i * 8 + (lane >> 3);
      int sc = cb ^ ((row & 7) << 4);
      g2l16((const char*)A + ((size_t)(m0 + row) * K + k0) * 2 + sc, (char*)As + i * 1024);
      g2l16((const char*)B + ((size_t)(n0 + row) * K + k0) * 2 + sc, (char*)Bs + i * 1024);
    }
    __syncthreads();
#pragma unroll
    for (int kh = 0; kh < 2; ++kh) {
      bf16x8 af[4], bfr[4];
#pragma unroll
      for (int m = 0; m < 4; ++m) {
        int row = wr * 64 + m * 16 + r16;
        int byte = row * 128 + ((g * 16 + kh * 64) ^ ((row & 7) << 4));
        af[m] = *(const bf16x8*)((const char*)As + byte);
      }
#pragma unroll
      for (int n = 0; n < 4; ++n) {
        int row = wc * 64 + n * 16 + r16;
        int byte = row * 128 + ((g * 16 + kh * 64) ^ ((row & 7) << 4));
        bfr[n] = *(const bf16x8*)((const char*)Bs + byte);
      }
#pragma unroll
      for (int m = 0; m < 4; ++m)
#pragma unroll
        for (int n = 0; n < 4; ++n)
          acc[m][n] = __builtin_amdgcn_mfma_f32_16x16x32_bf16(af[m], bfr[n], acc[m][n], 0, 0, 0);
    }
    __syncthreads();
  }

  if (y < 10) {
    // ---- q/k epilogue: RMSNorm + RoPE (+gain) -> LDS [tok128][d128] tile ----
    const bool isq = (y < 8);
    const int head = isq ? (2 * y + wc) : (2 * (y - 8) + wc);
    const float gain = isq ? qg[head] * 0.18033688011112042f : 1.0f;  // fold 1/8*log2e into q
    unsigned short* T = LDS;  // byte = tok*256 + ((d*2) ^ ((tok&15)<<4))
#pragma unroll
    for (int m = 0; m < 4; ++m)
#pragma unroll
      for (int j = 0; j < 4; ++j) {
        int tokl = wr * 64 + m * 16 + g * 4 + j;
        int tok = m0 + tokl;
        int s = tok & 2047;
        float v0 = acc[m][0][j], v1 = acc[m][1][j], v2 = acc[m][2][j], v3 = acc[m][3][j];
        float ss = v0 * v0 + v1 * v1 + v2 * v2 + v3 * v3;
        ss += __shfl_xor(ss, 1); ss += __shfl_xor(ss, 2);
        ss += __shfl_xor(ss, 4); ss += __shfl_xor(ss, 8);
        float rs = rsqrtf(ss * (1.0f / 64.0f) + 1e-6f) * gain;
        float2 cs0 = rope[s * 32 + r16];
        float2 cs1 = rope[s * 32 + 16 + r16];
        float o0 = (v0 * cs0.x + v2 * cs0.y) * rs;
        float o2 = (v2 * cs0.x - v0 * cs0.y) * rs;
        float o1 = (v1 * cs1.x + v3 * cs1.y) * rs;
        float o3 = (v3 * cs1.x - v1 * cs1.y) * rs;
        char* rowb = (char*)T + tokl * 256;
        const int sw = (tokl & 15) << 4;
        const int dbase = wc * 128 + r16 * 2;   // byte of d = wc*64 + r16
        *(unsigned short*)(rowb + ((dbase) ^ sw)) = f2bf(o0);
        *(unsigned short*)(rowb + ((dbase + 32) ^ sw)) = f2bf(o1);
        *(unsigned short*)(rowb + ((dbase + 64) ^ sw)) = f2bf(o2);
        *(unsigned short*)(rowb + ((dbase + 96) ^ sw)) = f2bf(o3);
      }
    __syncthreads();
    if (isq) {
      const int row0 = tid >> 4, cl = tid & 15;
      unsigned short* dstb = qn + 2 * y * 64;
#pragma unroll
      for (int it = 0; it < 8; ++it) {
        int row = it * 16 + row0;
        i32x4 w = *(const i32x4*)((const char*)T + row * 256 + ((cl * 16) ^ ((row & 15) << 4)));
        *(i32x4*)(dstb + (size_t)(m0 + row) * 1024 + cl * 8) = w;
      }
    } else {
      // ---- k: fragment-major stores straight from T ----
      const int b_ = m0 >> 11;
      const int kb0 = (m0 & 2047) >> 5;      // first 32-key block of this tile
      const int fu = tid >> 3, sub = tid & 7;
      const int hsel = fu >> 4, kb = (fu >> 2) & 3, m = fu & 3;
      const int headk = 2 * (y - 8) + hsel;
      unsigned short* dst =
          kn2 + ((size_t)((b_ * 4 + headk) * 64 + kb0 + kb) * 4 + m) * 512;
#pragma unroll
      for (int k = 0; k < 8; ++k) {
        int slot = k * 8 + sub;
        int kw = slot & 31, hi8 = slot >> 5;
        int tokl = kb * 32 + kw;
        int d0 = hsel * 64 + m * 16 + hi8 * 8;
        i32x4 w = *(const i32x4*)((const char*)T + tokl * 256 + ((d0 * 2) ^ ((tokl & 15) << 4)));
        *(i32x4*)(dst + slot * 8) = w;
      }
    }
  } else {
    // ---- v epilogue: LDS transpose -> fragment-major vt2 ----
    unsigned short* T = LDS;
#pragma unroll
    for (int m = 0; m < 4; ++m)
#pragma unroll
      for (int n = 0; n < 4; ++n)
#pragma unroll
        for (int j = 0; j < 4; ++j) {
          int tokl = wr * 64 + m * 16 + g * 4 + j;
          int dl = wc * 64 + n * 16 + r16;
          int byte = (dl * 256 + tokl * 2) ^ ((dl & 15) << 4);
          *(unsigned short*)((char*)T + byte) = f2bf(acc[m][n][j]);
        }
    __syncthreads();
    const int d = tid >> 1, th = tid & 1;
    const int hv = 2 * (y - 10) + (d >> 6), dh = d & 63;
    const int bb = m0 >> 11;
    const int s0 = (m0 & 2047) + th * 64;
    const int kb64 = s0 >> 6;
    const int db = dh >> 5, d31 = dh & 31;
    const size_t vb0 = ((size_t)(bb * 4 + hv) * 32 + kb64) * 8 + db * 4;
    const int swz = (d & 15) << 4;
#pragma unroll
    for (int c = 0; c < 8; ++c) {
      i32x4 w = *(const i32x4*)((const char*)T + ((d * 256 + th * 128 + c * 16) ^ swz));
      *(i32x4*)(vt2 + (vb0 + (c >> 1)) * 512 + ((c & 1) * 32 + d31) * 8) = w;
    }
  }
}

// ---------------- NT GEMM (m97) for out-proj ----------------
__global__ __launch_bounds__(256) void k_gemm_bt(const unsigned short* __restrict__ A,
                                                 const unsigned short* __restrict__ B,
                                                 float* __restrict__ C, int M, int N, int K) {
  __shared__ unsigned short As[128 * 64];
  __shared__ unsigned short Bs[128 * 64];
  const int tid = threadIdx.x;
  const int wid = tid >> 6, lane = tid & 63;
  const int g = lane >> 4, r16 = lane & 15;
  const int m0 = blockIdx.x * 128, n0 = blockIdx.y * 128;
  const int wr = wid >> 1, wc = wid & 1;

  f32x4 acc[4][4];
#pragma unroll
  for (int i = 0; i < 4; ++i)
#pragma unroll
    for (int j = 0; j < 4; ++j) acc[i][j] = f32x4{0.f, 0.f, 0.f, 0.f};

  const int cb = (lane & 7) * 16;

  for (int k0 = 0; k0 < K; k0 += 64) {
#pragma unroll
    for (int c = 0; c < 4; ++c) {
      int i = wid * 4 + c;
      int row = i * 8 + (lane >> 3);
      int sc = cb ^ ((row & 7) << 4);
      g2l16((const char*)A + ((size_t)(m0 + row) * K + k0) * 2 + sc, (char*)As + i * 1024);
      g2l16((const char*)B + ((size_t)(n0 + row) * K + k0) * 2 + sc, (char*)Bs + i * 1024);
    }
    __syncthreads();
#pragma unroll
    for (int kh = 0; kh < 2; ++kh) {
      bf16x8 af[4], bfr[4];
#pragma unroll
      for (int m = 0; m < 4; ++m) {
        int row = wr * 64 + m * 16 + r16;
        int byte = row * 128 + ((g * 16 + kh * 64) ^ ((row & 7) << 4));
        af[m] = *(const bf16x8*)((const char*)As + byte);
      }
#pragma unroll
      for (int n = 0; n < 4; ++n) {
        int row = wc * 64 + n * 16 + r16;
        int byte = row * 128 + ((g * 16 + kh * 64) ^ ((row & 7) << 4));
        bfr[n] = *(const bf16x8*)((const char*)Bs + byte);
      }
#pragma unroll
      for (int m = 0; m < 4; ++m)
#pragma unroll
        for (int n = 0; n < 4; ++n)
          acc[m][n] = __builtin_amdgcn_mfma_f32_16x16x32_bf16(af[m], bfr[n], acc[m][n], 0, 0, 0);
    }
    __syncthreads();
  }
#pragma unroll
  for (int m = 0; m < 4; ++m)
#pragma unroll
    for (int n = 0; n < 4; ++n)
#pragma unroll
      for (int j = 0; j < 4; ++j) {
        int row = m0 + wr * 64 + m * 16 + g * 4 + j;
        int col = n0 + wc * 64 + n * 16 + r16;
        C[(size_t)row * N + col] = acc[m][n][j];
      }
}

// ---------------- causal GQA flash attention, fragment-staged, 8-wave pair-pipelined ----
// (R13 configuration restored: 512 threads, 32 q-rows/wave, 16 waves/CU)
__global__ __launch_bounds__(512) void k_attn2(const unsigned short* __restrict__ qn,
                                               const unsigned short* __restrict__ kn2,
                                               const unsigned short* __restrict__ vt2,
                                               unsigned short* __restrict__ yb) {
  __shared__ unsigned short SMEM[4 * 8192];  // 4 tile-bufs x 16 frags x 1KB
  const int tid = threadIdx.x;
  const int wid = tid >> 6, lane = tid & 63;
  const int hi = lane >> 5, l31 = lane & 31;
  const int flat = blockIdx.x;
  const int qcx = 7 - (flat >> 6);  // longest blocks dispatch first
  const int bh = flat & 63;
  const int b = bh >> 4, h = bh & 15, hv = h >> 2;
  const int q0w = qcx * 256 + wid * 32;
  const int qglob = q0w + l31;
  const int tdiag = (q0w + 31) >> 6;  // wave's diagonal tile
  const size_t tok0 = (size_t)b * 2048;

  const u16x8 onesu = {0x3F80, 0x3F80, 0x3F80, 0x3F80, 0x3F80, 0x3F80, 0x3F80, 0x3F80};
  const bf16x8 ones = __builtin_bit_cast(bf16x8, onesu);

  bf16x8 qf[4];
#pragma unroll
  for (int m = 0; m < 4; ++m)
    qf[m] = *(const bf16x8*)(qn + (tok0 + qglob) * 1024 + h * 64 + m * 16 + hi * 8);

  f32x16 oacc[2], lacc, zer;
#pragma unroll
  for (int r = 0; r < 16; ++r) { oacc[0][r] = 0.f; oacc[1][r] = 0.f; lacc[r] = 0.f; zer[r] = 0.f; }

  // ---- per-wave fragment staging sources (linear, coalesced) ----
  const int c0 = wid * 2;
  const unsigned short* src0;
  if (wid < 4) {
    src0 = kn2 + (size_t)(b * 4 + hv) * 131072 + c0 * 512 + lane * 8;
  } else {
    src0 = vt2 + (size_t)(b * 4 + hv) * 131072 + (c0 - 8) * 512 + lane * 8;
  }
  const unsigned short* src1 = src0 + 512;

  auto stage = [&](int T, int tb) {
    char* dst = (char*)SMEM + tb * 16384 + c0 * 1024;
    g2l16(src0 + (size_t)T * 4096, dst);
    g2l16(src1 + (size_t)T * 4096, dst + 1024);
  };

  const char* lbase = (const char*)SMEM + lane * 16;

  auto qk_tile = [&](int tb, f32x16* s) {
    const char* base = lbase + tb * 16384;
#pragma unroll
    for (int kt = 0; kt < 2; ++kt) {
      __builtin_amdgcn_s_setprio(1);
      bf16x8 kf = *(const bf16x8*)(base + (kt * 4) * 1024);
      f32x16 a = __builtin_amdgcn_mfma_f32_32x32x16_bf16(kf, qf[0], zer, 0, 0, 0);
#pragma unroll
      for (int m = 1; m < 4; ++m) {
        kf = *(const bf16x8*)(base + (kt * 4 + m) * 1024);
        a = __builtin_amdgcn_mfma_f32_32x32x16_bf16(kf, qf[m], a, 0, 0, 0);
      }
      __builtin_amdgcn_s_setprio(0);
      s[kt] = a;
    }
  };

  auto mask_tile = [&](int t, f32x16* s) {
    const int k0 = t * 64;
#pragma unroll
    for (int kt = 0; kt < 2; ++kt)
#pragma unroll
      for (int r = 0; r < 16; ++r) {
        int key = k0 + kt * 32 + (r & 3) + 8 * (r >> 2) + 4 * hi;
        if (key > qglob) s[kt][r] = -INFINITY;
      }
  };

  auto softmax_cvt = [&](f32x16* s, i32x4* paw) {
#pragma unroll
    for (int kt = 0; kt < 2; ++kt)
#pragma unroll
      for (int r = 0; r < 16; ++r) s[kt][r] = fexp2(s[kt][r]);
#pragma unroll
    for (int kt = 0; kt < 2; ++kt)
#pragma unroll
      for (int half = 0; half < 2; ++half) {
        int bs = half * 8;
        unsigned int a0 = cvtpk(s[kt][bs + 0], s[kt][bs + 1]);
        unsigned int a1 = cvtpk(s[kt][bs + 2], s[kt][bs + 3]);
        unsigned int b0 = cvtpk(s[kt][bs + 4], s[kt][bs + 5]);
        unsigned int b1 = cvtpk(s[kt][bs + 6], s[kt][bs + 7]);
        i32x2 r0 = __builtin_amdgcn_permlane32_swap((int)a0, (int)b0, false, false);
        i32x2 r1 = __builtin_amdgcn_permlane32_swap((int)a1, (int)b1, false, false);
        i32x4 w;
        w[0] = r0[0]; w[1] = r1[0]; w[2] = r0[1]; w[3] = r1[1];
        paw[kt * 2 + half] = w;
      }
  };

  auto pv_tile = [&](int tb, const i32x4* paw) {
    const char* base = lbase + tb * 16384 + 8192;
    __builtin_amdgcn_s_setprio(1);
#pragma unroll
    for (int db = 0; db < 2; ++db)
#pragma unroll
      for (int ks = 0; ks < 4; ++ks) {
        bf16x8 vf = *(const bf16x8*)(base + (db * 4 + ks) * 1024);
        oacc[db] = __builtin_amdgcn_mfma_f32_32x32x16_bf16(
            vf, __builtin_bit_cast(bf16x8, paw[ks]), oacc[db], 0, 0, 0);
      }
#pragma unroll
    for (int ks = 0; ks < 4; ++ks)
      lacc = __builtin_amdgcn_mfma_f32_32x32x16_bf16(
          ones, __builtin_bit_cast(bf16x8, paw[ks]), lacc, 0, 0, 0);
    __builtin_amdgcn_s_setprio(0);
  };

  const int npair = 2 * qcx + 2;  // nt = 4*qcx + 4 tiles

  stage(0, 0);
  stage(1, 1);
  __syncthreads();

  for (int p = 0; p < npair; ++p) {
    const int pb = (p & 1) << 1;   // tile-bufs pb, pb|1
    if (p + 1 < npair) {
      stage(2 * p + 2, pb ^ 2);
      stage(2 * p + 3, (pb ^ 2) | 1);
    }
    const int t0 = 2 * p;
    const bool visa = (t0 <= tdiag), visb = (t0 + 1 <= tdiag);
    const bool domask = (p >= npair - 2);
    f32x16 sa[2], sb[2];
    if (visa) qk_tile(pb, sa);
    if (visb) qk_tile(pb | 1, sb);
    if (domask) {
      if (visa) mask_tile(t0, sa);
      if (visb) mask_tile(t0 + 1, sb);
    }
    i32x4 pawa[4], pawb[4];
    if (visa) {
      softmax_cvt(sa, pawa);
      pv_tile(pb, pawa);
    }
    if (visb) {
      softmax_cvt(sb, pawb);   // overlaps pv_tile(pb) MFMAs
      pv_tile(pb | 1, pawb);
    }
    __syncthreads();           // drains prefetch + frees bufs pb,pb|1
  }

  // ---- epilogue: O^T -> per-wave LDS transpose -> coalesced row store ----
  const float inv = 1.0f / lacc[0];
  const int swl = (l31 & 7) << 4;
  char* obase = (char*)SMEM + wid * 4096;
#pragma unroll
  for (int db = 0; db < 2; ++db)
#pragma unroll
    for (int i = 0; i < 8; ++i) {
      int r = 2 * i;
      int dim = db * 32 + (r & 3) + 8 * (r >> 2) + 4 * hi;
      unsigned int w = (unsigned int)f2bf(oacc[db][r] * inv) |
                       ((unsigned int)f2bf(oacc[db][r + 1] * inv) << 16);
      *(unsigned int*)(obase + l31 * 128 + ((dim * 2) ^ swl)) = w;
    }
  __syncthreads();
#pragma unroll
  for (int it = 0; it < 4; ++it) {
    int cc = it * 2 + hi;
    i32x4 w = *(const i32x4*)(obase + l31 * 128 + ((cc * 16) ^ swl));
    *(i32x4*)(yb + (tok0 + q0w + l31) * 1024 + h * 64 + cc * 8) = w;
  }
}

// ---------------- launch ----------------
extern "C" void kernel_launch(void* const* d_in, const int* in_sizes, int n_in,
                              void* d_out, int out_size, void* d_ws, size_t ws_size,
                              hipStream_t stream) {
  (void)in_sizes; (void)n_in; (void)out_size; (void)ws_size;
  const float* x  = (const float*)d_in[0];
  const float* Wq = (const float*)d_in[1];
  const float* Wk = (const float*)d_in[2];
  const float* Wv = (const float*)d_in[3];
  const float* Wo = (const float*)d_in[4];
  const float* qg = (const float*)d_in[5];

  char* ws = (char*)d_ws;
  unsigned short* xb   = (unsigned short*)(ws);             // 16 MB  [8192][1024]
  unsigned short* wcat = (unsigned short*)(ws + 16777216);  // 3 MB   [1536][1024]
  unsigned short* wob  = (unsigned short*)(ws + 19922944);  // 2 MB   [1024][1024]
  unsigned short* qn   = (unsigned short*)(ws + 22020096);  // 16 MB  [8192][1024]
  unsigned short* kn2  = (unsigned short*)(ws + 38797312);  // 4 MB   fragment-major K
  unsigned short* yb   = xb;                                // alias: xb dead after k_qkv
  unsigned short* vt2  = (unsigned short*)((char*)d_out + 25165824);  // 4 MB fragment-major V
  float2*         rope = (float2*)((char*)d_out + 29360128);          // 512 KB [2048][32]

  k_cvt_all<<<5632, 256, 0, stream>>>(x, Wq, Wk, Wv, Wo, xb, wcat, wob, rope);
  k_qkv<<<dim3(64, 12), 256, 0, stream>>>(xb, wcat, qg, rope, qn, kn2, vt2);
  k_attn2<<<512, 512, 0, stream>>>(qn, kn2, vt2, yb);
  k_gemm_bt<<<dim3(64, 8), 256, 0, stream>>>(yb, wob, (float*)d_out, 8192, 1024, 1024);
}